// Round 4
// baseline (32.054 us; speedup 1.0000x reference)
//
#include <hip/hip_runtime.h>

#define MAXF 4096
#define CG 8          // channels per block

typedef float f32x4 __attribute__((ext_vector_type(4)));
typedef int   i32x4 __attribute__((ext_vector_type(4)));

// ---------------------------------------------------------------------------
// Fused: per block = (batch b, channel-group of CG).
//  1. wave-shfl scan of ds[b,:] (6 shfl steps + 8-wavesum combine, 2 barriers)
//  2. scatter-build idx table in LDS (== searchsorted(cum, pos, 'right'));
//     only tail [total, MAXF) needs the -1 init
//  3. gather CG channels; idx quad reused in registers; nontemporal float4
//     stores (output never re-read -> don't pollute L2)
//  4. cg==0 block also writes pitch + total
// ---------------------------------------------------------------------------
__global__ __launch_bounds__(512) void lr_fused(
    const float* __restrict__ xs,         // (B, C, T)
    const float* __restrict__ notepitch,  // (B, T)
    const int* __restrict__ ds,           // (B, T)
    float* __restrict__ out,              // (B, C, MAXF)
    float* __restrict__ pitch_out,        // (B, MAXF)
    float* __restrict__ total_out,        // (B,) as float
    int T, int C)
{
    const int b    = blockIdx.y;
    const int cg   = blockIdx.x;
    const int t    = threadIdx.x;
    const int lane = t & 63;
    const int wid  = t >> 6;      // 0..7

    __shared__ int wsum[8];
    __shared__ int idx_sh[MAXF];

    // ---- wave-level inclusive scan of ds ----
    int v = (t < T) ? ds[b * T + t] : 0;
    int s = v;
#pragma unroll
    for (int off = 1; off < 64; off <<= 1) {
        int y = __shfl_up(s, off, 64);
        if (lane >= off) s += y;
    }
    if (lane == 63) wsum[wid] = s;
    __syncthreads();

    int woff = 0, total = 0;
#pragma unroll
    for (int w = 0; w < 8; ++w) {
        int ws = wsum[w];
        woff  += (w < wid) ? ws : 0;
        total += ws;
    }
    int cum = s + woff;           // inclusive cumsum at position t

    if (total == 0) {             // row_zero: ds -> all ones
        cum = t + 1;
        v = 1;
        total = T;
    }

    // ---- scatter: positions [cum-v, cum) <- t ----
    if (t < T && v > 0) {
        int hi = (cum < MAXF) ? cum : MAXF;
        for (int p = cum - v; p < hi; ++p) idx_sh[p] = t;
    }
    // tail: positions >= total are masked
    for (int p = total + t; p < MAXF; p += 512) idx_sh[p] = -1;
    __syncthreads();

    // ---- gather + write ----
    const float* __restrict__ xbase = xs  + ((size_t)b * C + (size_t)cg * CG) * T;
    float* __restrict__       obase = out + ((size_t)b * C + (size_t)cg * CG) * MAXF;

#pragma unroll
    for (int i = 0; i < MAXF / (512 * 4); ++i) {   // 2 iterations
        const int p4 = (i * 512 + t) * 4;
        i32x4 id = *reinterpret_cast<const i32x4*>(&idx_sh[p4]);
#pragma unroll
        for (int ch = 0; ch < CG; ++ch) {
            const float* __restrict__ xrow = xbase + (size_t)ch * T;
            f32x4 vv;
            vv.x = (id.x >= 0) ? xrow[id.x] : 0.0f;
            vv.y = (id.y >= 0) ? xrow[id.y] : 0.0f;
            vv.z = (id.z >= 0) ? xrow[id.z] : 0.0f;
            vv.w = (id.w >= 0) ? xrow[id.w] : 0.0f;
            __builtin_nontemporal_store(vv, reinterpret_cast<f32x4*>(obase + (size_t)ch * MAXF + p4));
        }
    }

    if (cg == 0) {
        for (int p = t; p < MAXF; p += 512) {
            int id = idx_sh[p];
            pitch_out[(size_t)b * MAXF + p] = (id >= 0) ? notepitch[b * T + id] : 0.0f;
        }
        if (t == 0) total_out[b] = (float)total;
    }
}

extern "C" void kernel_launch(void* const* d_in, const int* in_sizes, int n_in,
                              void* d_out, int out_size, void* d_ws, size_t ws_size,
                              hipStream_t stream) {
    const float* xs        = (const float*)d_in[0];
    const float* notepitch = (const float*)d_in[1];
    const int*   ds        = (const int*)d_in[2];
    // d_in[3] = x_lengths: unused by the reference computation

    const int B = in_sizes[3];
    const int T = in_sizes[1] / B;
    const int C = in_sizes[0] / (B * T);

    float* out       = (float*)d_out;
    float* pitch_out = out + (size_t)B * C * MAXF;
    float* total_out = pitch_out + (size_t)B * MAXF;

    dim3 grid(C / CG, B);
    lr_fused<<<grid, 512, 0, stream>>>(xs, notepitch, ds, out, pitch_out, total_out, T, C);
}

// Round 5
// 28.009 us; speedup vs baseline: 1.1444x; 1.1444x over previous
//
#include <hip/hip_runtime.h>

#define MAXF 4096
#define CG 8          // channels per block

typedef float f32x4 __attribute__((ext_vector_type(4)));
typedef int   i32x4 __attribute__((ext_vector_type(4)));

// ---------------------------------------------------------------------------
// Fused: per block = (batch b, channel-group of CG).
//  1. wave-shfl scan of ds[b,:] (6 shfl steps + 8-wavesum combine, 2 barriers)
//  2. scatter-build idx table in LDS (== searchsorted(cum, pos, 'right'));
//     only tail [total, MAXF) needs the -1 init
//  3. gather CG channels; idx quad reused in registers; plain float4 stores
//     (nontemporal REGRESSED: r4 32.0 vs r2 28.8 — L2 write path is faster)
//  4. cg==0 block also writes pitch + total
// ---------------------------------------------------------------------------
__global__ __launch_bounds__(512) void lr_fused(
    const float* __restrict__ xs,         // (B, C, T)
    const float* __restrict__ notepitch,  // (B, T)
    const int* __restrict__ ds,           // (B, T)
    float* __restrict__ out,              // (B, C, MAXF)
    float* __restrict__ pitch_out,        // (B, MAXF)
    float* __restrict__ total_out,        // (B,) as float
    int T, int C)
{
    const int b    = blockIdx.y;
    const int cg   = blockIdx.x;
    const int t    = threadIdx.x;
    const int lane = t & 63;
    const int wid  = t >> 6;      // 0..7

    __shared__ int wsum[8];
    __shared__ int idx_sh[MAXF];

    // ---- wave-level inclusive scan of ds ----
    int v = (t < T) ? ds[b * T + t] : 0;
    int s = v;
#pragma unroll
    for (int off = 1; off < 64; off <<= 1) {
        int y = __shfl_up(s, off, 64);
        if (lane >= off) s += y;
    }
    if (lane == 63) wsum[wid] = s;
    __syncthreads();

    int woff = 0, total = 0;
#pragma unroll
    for (int w = 0; w < 8; ++w) {
        int ws = wsum[w];
        woff  += (w < wid) ? ws : 0;
        total += ws;
    }
    int cum = s + woff;           // inclusive cumsum at position t

    if (total == 0) {             // row_zero: ds -> all ones
        cum = t + 1;
        v = 1;
        total = T;
    }

    // ---- scatter: positions [cum-v, cum) <- t ----
    if (t < T && v > 0) {
        int hi = (cum < MAXF) ? cum : MAXF;
        for (int p = cum - v; p < hi; ++p) idx_sh[p] = t;
    }
    // tail: positions >= total are masked
    for (int p = total + t; p < MAXF; p += 512) idx_sh[p] = -1;
    __syncthreads();

    // ---- gather + write ----
    const float* __restrict__ xbase = xs  + ((size_t)b * C + (size_t)cg * CG) * T;
    float* __restrict__       obase = out + ((size_t)b * C + (size_t)cg * CG) * MAXF;

#pragma unroll
    for (int i = 0; i < MAXF / (512 * 4); ++i) {   // 2 iterations
        const int p4 = (i * 512 + t) * 4;
        i32x4 id = *reinterpret_cast<const i32x4*>(&idx_sh[p4]);
#pragma unroll
        for (int ch = 0; ch < CG; ++ch) {
            const float* __restrict__ xrow = xbase + (size_t)ch * T;
            f32x4 vv;
            vv.x = (id.x >= 0) ? xrow[id.x] : 0.0f;
            vv.y = (id.y >= 0) ? xrow[id.y] : 0.0f;
            vv.z = (id.z >= 0) ? xrow[id.z] : 0.0f;
            vv.w = (id.w >= 0) ? xrow[id.w] : 0.0f;
            *reinterpret_cast<f32x4*>(obase + (size_t)ch * MAXF + p4) = vv;
        }
    }

    if (cg == 0) {
        for (int p = t; p < MAXF; p += 512) {
            int id = idx_sh[p];
            pitch_out[(size_t)b * MAXF + p] = (id >= 0) ? notepitch[b * T + id] : 0.0f;
        }
        if (t == 0) total_out[b] = (float)total;
    }
}

extern "C" void kernel_launch(void* const* d_in, const int* in_sizes, int n_in,
                              void* d_out, int out_size, void* d_ws, size_t ws_size,
                              hipStream_t stream) {
    const float* xs        = (const float*)d_in[0];
    const float* notepitch = (const float*)d_in[1];
    const int*   ds        = (const int*)d_in[2];
    // d_in[3] = x_lengths: unused by the reference computation

    const int B = in_sizes[3];
    const int T = in_sizes[1] / B;
    const int C = in_sizes[0] / (B * T);

    float* out       = (float*)d_out;
    float* pitch_out = out + (size_t)B * C * MAXF;
    float* total_out = pitch_out + (size_t)B * MAXF;

    dim3 grid(C / CG, B);
    lr_fused<<<grid, 512, 0, stream>>>(xs, notepitch, ds, out, pitch_out, total_out, T, C);
}